// Round 1
// baseline (246.139 us; speedup 1.0000x reference)
//
#include <hip/hip_runtime.h>
#include <stdint.h>

#define BSz 4096   // B*S tokens
#define Ddim 1024
#define Fdim 4096
#define Edim 4
#define Rdim 4

typedef __attribute__((ext_vector_type(8))) short bf16x8;
typedef __attribute__((ext_vector_type(4))) float f32x4;

__device__ __forceinline__ unsigned short f2bf(float f) {
  union { float f; uint32_t u; } c; c.f = f;
  return (unsigned short)((c.u + 0x7fffu + ((c.u >> 16) & 1u)) >> 16);
}

// ---------------- fp32 -> bf16 conversion (vectorized) ----------------
__global__ __launch_bounds__(256) void cvt_kernel(const float* __restrict__ in,
                                                  unsigned short* __restrict__ out,
                                                  int n4) {
  int i = blockIdx.x * 256 + threadIdx.x;
  if (i < n4) {
    float4 v = ((const float4*)in)[i];
    ushort4 o;
    o.x = f2bf(v.x); o.y = f2bf(v.y); o.z = f2bf(v.z); o.w = f2bf(v.w);
    ((ushort4*)out)[i] = o;
  }
}

// ---------------- router: logits -> softmax -> top2 + lora_low ----------------
// meta[t][0..15]: e0, e1, w0, w1, ll0[0..3], ll1[0..3], pad
__global__ __launch_bounds__(256) void router_kernel(const float* __restrict__ x,
                                                     const float* __restrict__ Wg,
                                                     const float* __restrict__ bg,
                                                     const float* __restrict__ Aw,
                                                     float* __restrict__ meta) {
  __shared__ float xs[Ddim];
  __shared__ float dots[Edim + Edim * Rdim];
  const int t = blockIdx.x;
  const float4* xt = (const float4*)(x + (size_t)t * Ddim);
  for (int i = threadIdx.x; i < Ddim / 4; i += 256) ((float4*)xs)[i] = xt[i];
  __syncthreads();
  const int wave = threadIdx.x >> 6, lane = threadIdx.x & 63;
  // 20 dot products: 4 logits + 16 lora_low; 5 per wave
  for (int d = wave * 5; d < wave * 5 + 5; ++d) {
    const float* wrow = (d < Edim) ? (Wg + (size_t)d * Ddim)
                                   : (Aw + (size_t)(d - Edim) * Ddim);
    float s = 0.f;
    for (int i = lane; i < Ddim; i += 64) s += xs[i] * wrow[i];
    for (int off = 32; off; off >>= 1) s += __shfl_down(s, off);
    if (lane == 0) dots[d] = s;
  }
  __syncthreads();
  if (threadIdx.x == 0) {
    float p[Edim];
    float m = -1e30f;
    for (int e = 0; e < Edim; ++e) { p[e] = dots[e] + bg[e]; m = fmaxf(m, p[e]); }
    float sum = 0.f;
    for (int e = 0; e < Edim; ++e) { p[e] = expf(p[e] - m); sum += p[e]; }
    const float inv = 1.f / sum;
    for (int e = 0; e < Edim; ++e) p[e] *= inv;
    int e0 = 0;
    for (int e = 1; e < Edim; ++e) if (p[e] > p[e0]) e0 = e;   // ties -> lowest idx
    int e1 = (e0 == 0) ? 1 : 0;
    for (int e = 0; e < Edim; ++e) if (e != e0 && p[e] > p[e1]) e1 = e;
    float* mt = meta + (size_t)t * 16;
    mt[0] = (float)e0; mt[1] = (float)e1; mt[2] = p[e0]; mt[3] = p[e1];
    for (int r = 0; r < Rdim; ++r) {
      mt[4 + r] = dots[Edim + e0 * Rdim + r];
      mt[8 + r] = dots[Edim + e1 * Rdim + r];
    }
    mt[12] = 0.f; mt[13] = 0.f; mt[14] = 0.f; mt[15] = 0.f;
  }
}

// ---------------- NT bf16 GEMM: C[M,N] = A[M,K] * B[N,K]^T ----------------
// EPI==0: fused MoE epilogue -> g[t,f] (bf16).  EPI==1: plain fp32 store.
template <int EPI>
__global__ __launch_bounds__(256) void gemm_nt(const unsigned short* __restrict__ Ag,
                                               const unsigned short* __restrict__ Bg,
                                               int M, int N, int K,
                                               const float* __restrict__ meta,
                                               const float* __restrict__ B2,
                                               unsigned short* __restrict__ outg,
                                               float* __restrict__ outf) {
  constexpr int BM = 128, BN = 128, BK = 64;
  __shared__ __align__(16) unsigned short sA[BM * BK];
  __shared__ __align__(16) unsigned short sB[BN * BK];
  const int tid = threadIdx.x;
  const int lane = tid & 63;
  const int wave = tid >> 6;
  const int wr = wave >> 1, wc = wave & 1;      // 2x2 waves of 64x64 each
  const int l16 = lane & 15, lhi = lane >> 4;
  const int bm = blockIdx.y * BM, bn = blockIdx.x * BN;

  f32x4 acc[4][4] = {};

  // staging: per round rr (4 rounds), thread tid covers 16B at tile elem off = tid*8 + rr*2048
  const int eoff = tid * 8;
  const int srow = eoff >> 6;        // tid/8
  const int scol = eoff & 63;        // (tid%8)*8
  const size_t arow = (size_t)(bm + srow) * K + scol;
  const size_t brow = (size_t)(bn + srow) * K + scol;

  for (int kt = 0; kt < K; kt += BK) {
#pragma unroll
    for (int rr = 0; rr < 4; ++rr) {
      __builtin_amdgcn_global_load_lds(
          (const __attribute__((address_space(1))) void*)(Ag + arow + (size_t)rr * 32 * K + kt),
          (__attribute__((address_space(3))) void*)(sA + eoff + rr * 2048), 16, 0, 0);
      __builtin_amdgcn_global_load_lds(
          (const __attribute__((address_space(1))) void*)(Bg + brow + (size_t)rr * 32 * K + kt),
          (__attribute__((address_space(3))) void*)(sB + eoff + rr * 2048), 16, 0, 0);
    }
    __syncthreads();
#pragma unroll
    for (int kk = 0; kk < 2; ++kk) {
      bf16x8 af[4], bf[4];
#pragma unroll
      for (int i = 0; i < 4; ++i) {
        af[i] = *(const bf16x8*)(sA + (wr * 64 + i * 16 + l16) * BK + kk * 32 + lhi * 8);
        bf[i] = *(const bf16x8*)(sB + (wc * 64 + i * 16 + l16) * BK + kk * 32 + lhi * 8);
      }
#pragma unroll
      for (int i = 0; i < 4; ++i)
#pragma unroll
        for (int j = 0; j < 4; ++j)
          acc[i][j] = __builtin_amdgcn_mfma_f32_16x16x32_bf16(af[i], bf[j], acc[i][j], 0, 0, 0);
    }
    __syncthreads();
  }

  if (EPI == 0) {
    // g[t,f] = sum_{e in top2} w_e * relu(base + <ll_e, B2[e,f,:]>)
#pragma unroll
    for (int mi = 0; mi < 4; ++mi) {
#pragma unroll
      for (int r = 0; r < 4; ++r) {
        const int t = bm + wr * 64 + mi * 16 + lhi * 4 + r;
        const float* mt = meta + (size_t)t * 16;
        const int e0 = (int)mt[0], e1 = (int)mt[1];
        const float w0 = mt[2], w1 = mt[3];
        const float4 l0 = *(const float4*)(mt + 4);
        const float4 l1 = *(const float4*)(mt + 8);
#pragma unroll
        for (int ni = 0; ni < 4; ++ni) {
          const int f = bn + wc * 64 + ni * 16 + l16;
          const float4 b0 = *(const float4*)(B2 + ((size_t)e0 * Fdim + f) * Rdim);
          const float4 b1 = *(const float4*)(B2 + ((size_t)e1 * Fdim + f) * Rdim);
          const float a = acc[mi][ni][r];
          const float lora0 = l0.x * b0.x + l0.y * b0.y + l0.z * b0.z + l0.w * b0.w;
          const float lora1 = l1.x * b1.x + l1.y * b1.y + l1.z * b1.z + l1.w * b1.w;
          const float gv = w0 * fmaxf(a + lora0, 0.f) + w1 * fmaxf(a + lora1, 0.f);
          outg[(size_t)t * Fdim + f] = f2bf(gv);
        }
      }
    }
  } else {
#pragma unroll
    for (int mi = 0; mi < 4; ++mi)
#pragma unroll
      for (int ni = 0; ni < 4; ++ni)
#pragma unroll
        for (int r = 0; r < 4; ++r) {
          const int t = bm + wr * 64 + mi * 16 + lhi * 4 + r;
          const int dcol = bn + wc * 64 + ni * 16 + l16;
          outf[(size_t)t * N + dcol] = acc[mi][ni][r];
        }
  }
}

extern "C" void kernel_launch(void* const* d_in, const int* in_sizes, int n_in,
                              void* d_out, int out_size, void* d_ws, size_t ws_size,
                              hipStream_t stream) {
  const float* x  = (const float*)d_in[0];
  const float* Wg = (const float*)d_in[1];
  const float* bg = (const float*)d_in[2];
  const float* Wi = (const float*)d_in[3];
  const float* Wo = (const float*)d_in[4];
  const float* Aw = (const float*)d_in[5];
  const float* B2 = (const float*)d_in[6];
  float* out = (float*)d_out;

  // workspace layout (bf16 as ushort)
  unsigned short* xb  = (unsigned short*)d_ws;                 // [BSz][Ddim]   8 MB
  unsigned short* wib = xb  + (size_t)BSz  * Ddim;             // [Fdim][Ddim]  8 MB
  unsigned short* wob = wib + (size_t)Fdim * Ddim;             // [Ddim][Fdim]  8 MB
  unsigned short* g   = wob + (size_t)Ddim * Fdim;             // [BSz][Fdim]  32 MB
  float* meta = (float*)(g + (size_t)BSz * Fdim);              // [BSz][16]   256 KB

  const int n4x = BSz * Ddim / 4;   // also Fdim*Ddim/4 and Ddim*Fdim/4 (all equal)
  cvt_kernel<<<(n4x + 255) / 256, 256, 0, stream>>>(x,  xb,  n4x);
  cvt_kernel<<<(n4x + 255) / 256, 256, 0, stream>>>(Wi, wib, n4x);
  cvt_kernel<<<(n4x + 255) / 256, 256, 0, stream>>>(Wo, wob, n4x);

  router_kernel<<<BSz, 256, 0, stream>>>(x, Wg, bg, Aw, meta);

  // GEMM1: base = x * Wi^T with fused lora+relu+combine epilogue -> g (bf16)
  gemm_nt<0><<<dim3(Fdim / 128, BSz / 128), 256, 0, stream>>>(
      xb, wib, BSz, Fdim, Ddim, meta, B2, g, nullptr);

  // GEMM2: out = g * Wo^T (fp32 store)
  gemm_nt<1><<<dim3(Ddim / 128, BSz / 128), 256, 0, stream>>>(
      g, wob, BSz, Ddim, Fdim, nullptr, nullptr, nullptr, out);
}

// Round 2
// 201.687 us; speedup vs baseline: 1.2204x; 1.2204x over previous
//
#include <hip/hip_runtime.h>
#include <stdint.h>

#define BSz 4096   // B*S tokens
#define Ddim 1024
#define Fdim 4096
#define Edim 4
#define Rdim 4

typedef __attribute__((ext_vector_type(8))) short bf16x8;
typedef __attribute__((ext_vector_type(4))) float f32x4;

__device__ __forceinline__ unsigned short f2bf(float f) {
  union { float f; uint32_t u; } c; c.f = f;
  return (unsigned short)((c.u + 0x7fffu + ((c.u >> 16) & 1u)) >> 16);
}

// ---------------- fp32 -> bf16 conversion (vectorized) ----------------
__global__ __launch_bounds__(256) void cvt_kernel(const float* __restrict__ in,
                                                  unsigned short* __restrict__ out,
                                                  int n4) {
  int i = blockIdx.x * 256 + threadIdx.x;
  if (i < n4) {
    float4 v = ((const float4*)in)[i];
    ushort4 o;
    o.x = f2bf(v.x); o.y = f2bf(v.y); o.z = f2bf(v.z); o.w = f2bf(v.w);
    ((ushort4*)out)[i] = o;
  }
}

// ---------------- router: logits -> softmax -> top2 + lora_low ----------------
// meta[t][0..15]: e0, e1, w0, w1, ll0[0..3], ll1[0..3], pad
__global__ __launch_bounds__(256) void router_kernel(const float* __restrict__ x,
                                                     const float* __restrict__ Wg,
                                                     const float* __restrict__ bg,
                                                     const float* __restrict__ Aw,
                                                     float* __restrict__ meta) {
  __shared__ float xs[Ddim];
  __shared__ float dots[Edim + Edim * Rdim];
  const int t = blockIdx.x;
  const float4* xt = (const float4*)(x + (size_t)t * Ddim);
  for (int i = threadIdx.x; i < Ddim / 4; i += 256) ((float4*)xs)[i] = xt[i];
  __syncthreads();
  const int wave = threadIdx.x >> 6, lane = threadIdx.x & 63;
  for (int d = wave * 5; d < wave * 5 + 5; ++d) {
    const float* wrow = (d < Edim) ? (Wg + (size_t)d * Ddim)
                                   : (Aw + (size_t)(d - Edim) * Ddim);
    float s = 0.f;
    for (int i = lane; i < Ddim; i += 64) s += xs[i] * wrow[i];
    for (int off = 32; off; off >>= 1) s += __shfl_down(s, off);
    if (lane == 0) dots[d] = s;
  }
  __syncthreads();
  if (threadIdx.x == 0) {
    float p[Edim];
    float m = -1e30f;
    for (int e = 0; e < Edim; ++e) { p[e] = dots[e] + bg[e]; m = fmaxf(m, p[e]); }
    float sum = 0.f;
    for (int e = 0; e < Edim; ++e) { p[e] = expf(p[e] - m); sum += p[e]; }
    const float inv = 1.f / sum;
    for (int e = 0; e < Edim; ++e) p[e] *= inv;
    int e0 = 0;
    for (int e = 1; e < Edim; ++e) if (p[e] > p[e0]) e0 = e;
    int e1 = (e0 == 0) ? 1 : 0;
    for (int e = 0; e < Edim; ++e) if (e != e0 && p[e] > p[e1]) e1 = e;
    float* mt = meta + (size_t)t * 16;
    mt[0] = (float)e0; mt[1] = (float)e1; mt[2] = p[e0]; mt[3] = p[e1];
    for (int r = 0; r < Rdim; ++r) {
      mt[4 + r] = dots[Edim + e0 * Rdim + r];
      mt[8 + r] = dots[Edim + e1 * Rdim + r];
    }
    mt[12] = 0.f; mt[13] = 0.f; mt[14] = 0.f; mt[15] = 0.f;
  }
}

// ---------------- 2-phase double-buffered NT bf16 GEMM ----------------
// C[M,N] = A[M,K] * B[N,K]^T
// EPI==0: fused MoE epilogue -> g[t,f] (bf16).  EPI==1: plain fp32 store.
template <int BM, int BN, int WMv, int WNv, int EPI>
__global__ __launch_bounds__(WMv * WNv * 64, 2)
void gemm2ph(const unsigned short* __restrict__ Ag,
             const unsigned short* __restrict__ Bg,
             int M, int N, int K,
             const float* __restrict__ meta,
             const float* __restrict__ B2,
             unsigned short* __restrict__ outg,
             float* __restrict__ outf) {
  constexpr int BK = 32;
  constexpr int NTHREADS = WMv * WNv * 64;
  constexpr int WROWS = BM / WMv;        // per-wave output rows
  constexpr int WCOLS = BN / WNv;        // per-wave output cols
  constexpr int MR = WROWS / 16;
  constexpr int NR = WCOLS / 16;
  constexpr int RPR = NTHREADS / 4;      // staged rows per round (BK=32: 4 thr/row)
  constexpr int NRA = BM / RPR;
  constexpr int NRB = BN / RPR;

  __shared__ __align__(16) unsigned short sA[2][BM * BK];
  __shared__ __align__(16) unsigned short sB[2][BN * BK];

  const int tid = threadIdx.x;
  const int lane = tid & 63;
  const int wave = tid >> 6;
  const int wr = wave / WNv, wc = wave % WNv;
  const int l16 = lane & 15, lhi = lane >> 4;
  const int bm = blockIdx.y * BM, bn = blockIdx.x * BN;

  f32x4 acc[MR][NR] = {};

  const int eoff = tid * 8;              // LDS element offset (linear, lane-contiguous)
  const int srow = tid >> 2;             // staged row within round
  const int scol = (tid & 3) * 8;
  const size_t abase = (size_t)(bm + srow) * K + scol;
  const size_t bbase = (size_t)(bn + srow) * K + scol;

  auto stage = [&](int buf, int kt) {
#pragma unroll
    for (int rr = 0; rr < NRA; ++rr)
      __builtin_amdgcn_global_load_lds(
          (const __attribute__((address_space(1))) void*)(Ag + abase + (size_t)rr * RPR * K + kt),
          (__attribute__((address_space(3))) void*)(&sA[buf][eoff + rr * RPR * BK]), 16, 0, 0);
#pragma unroll
    for (int rr = 0; rr < NRB; ++rr)
      __builtin_amdgcn_global_load_lds(
          (const __attribute__((address_space(1))) void*)(Bg + bbase + (size_t)rr * RPR * K + kt),
          (__attribute__((address_space(3))) void*)(&sB[buf][eoff + rr * RPR * BK]), 16, 0, 0);
  };

  auto compute = [&](int buf) {
    bf16x8 af[MR], bfv[NR];
#pragma unroll
    for (int i = 0; i < MR; ++i)
      af[i] = *(const bf16x8*)(&sA[buf][(wr * WROWS + i * 16 + l16) * BK + lhi * 8]);
#pragma unroll
    for (int j = 0; j < NR; ++j)
      bfv[j] = *(const bf16x8*)(&sB[buf][(wc * WCOLS + j * 16 + l16) * BK + lhi * 8]);
#pragma unroll
    for (int i = 0; i < MR; ++i)
#pragma unroll
      for (int j = 0; j < NR; ++j)
        acc[i][j] = __builtin_amdgcn_mfma_f32_16x16x32_bf16(af[i], bfv[j], acc[i][j], 0, 0, 0);
  };

  const int NT = K / BK;
  // prologue
  stage(0, 0);
  asm volatile("s_waitcnt vmcnt(0)" ::: "memory");
  __builtin_amdgcn_s_barrier();
  asm volatile("" ::: "memory");

  int cur = 0;
  for (int t = 0; t < NT - 1; ++t) {
    stage(cur ^ 1, (t + 1) * BK);      // prefetch next tile (stays in flight)
    compute(cur);                       // ds_read + MFMA current tile
    asm volatile("s_waitcnt vmcnt(0)" ::: "memory");  // next tile landed
    __builtin_amdgcn_s_barrier();
    asm volatile("" ::: "memory");
    cur ^= 1;
  }
  compute(cur);                         // epilogue tile

  if (EPI == 0) {
    // g[t,f] = sum_{e in top2} w_e * relu(base + <ll_e, B2[e,f,:]>)
#pragma unroll
    for (int mi = 0; mi < MR; ++mi) {
#pragma unroll
      for (int r = 0; r < 4; ++r) {
        const int t = bm + wr * WROWS + mi * 16 + lhi * 4 + r;
        const float* mt = meta + (size_t)t * 16;
        const int e0 = (int)mt[0], e1 = (int)mt[1];
        const float w0 = mt[2], w1 = mt[3];
        const float4 l0 = *(const float4*)(mt + 4);
        const float4 l1 = *(const float4*)(mt + 8);
#pragma unroll
        for (int ni = 0; ni < NR; ++ni) {
          const int f = bn + wc * WCOLS + ni * 16 + l16;
          const float4 b0 = *(const float4*)(B2 + ((size_t)e0 * Fdim + f) * Rdim);
          const float4 b1 = *(const float4*)(B2 + ((size_t)e1 * Fdim + f) * Rdim);
          const float a = acc[mi][ni][r];
          const float lora0 = l0.x * b0.x + l0.y * b0.y + l0.z * b0.z + l0.w * b0.w;
          const float lora1 = l1.x * b1.x + l1.y * b1.y + l1.z * b1.z + l1.w * b1.w;
          const float gv = w0 * fmaxf(a + lora0, 0.f) + w1 * fmaxf(a + lora1, 0.f);
          outg[(size_t)t * Fdim + f] = f2bf(gv);
        }
      }
    }
  } else {
#pragma unroll
    for (int mi = 0; mi < MR; ++mi)
#pragma unroll
      for (int ni = 0; ni < NR; ++ni)
#pragma unroll
        for (int r = 0; r < 4; ++r) {
          const int t = bm + wr * WROWS + mi * 16 + lhi * 4 + r;
          const int dcol = bn + wc * WCOLS + ni * 16 + l16;
          outf[(size_t)t * N + dcol] = acc[mi][ni][r];
        }
  }
}

extern "C" void kernel_launch(void* const* d_in, const int* in_sizes, int n_in,
                              void* d_out, int out_size, void* d_ws, size_t ws_size,
                              hipStream_t stream) {
  const float* x  = (const float*)d_in[0];
  const float* Wg = (const float*)d_in[1];
  const float* bg = (const float*)d_in[2];
  const float* Wi = (const float*)d_in[3];
  const float* Wo = (const float*)d_in[4];
  const float* Aw = (const float*)d_in[5];
  const float* B2 = (const float*)d_in[6];
  float* out = (float*)d_out;

  // workspace layout (bf16 as ushort)
  unsigned short* xb  = (unsigned short*)d_ws;                 // [BSz][Ddim]   8 MB
  unsigned short* wib = xb  + (size_t)BSz  * Ddim;             // [Fdim][Ddim]  8 MB
  unsigned short* wob = wib + (size_t)Fdim * Ddim;             // [Ddim][Fdim]  8 MB
  unsigned short* g   = wob + (size_t)Ddim * Fdim;             // [BSz][Fdim]  32 MB
  float* meta = (float*)(g + (size_t)BSz * Fdim);              // [BSz][16]   256 KB

  const int n4x = BSz * Ddim / 4;   // == Fdim*Ddim/4 == Ddim*Fdim/4
  cvt_kernel<<<(n4x + 255) / 256, 256, 0, stream>>>(x,  xb,  n4x);
  cvt_kernel<<<(n4x + 255) / 256, 256, 0, stream>>>(Wi, wib, n4x);
  cvt_kernel<<<(n4x + 255) / 256, 256, 0, stream>>>(Wo, wob, n4x);

  router_kernel<<<BSz, 256, 0, stream>>>(x, Wg, bg, Aw, meta);

  // GEMM1: base = x * Wi^T, fused lora+relu+combine epilogue -> g (bf16)
  // 256x256 tile, 8 waves, grid 16x16 = 256 blocks (1/CU)
  gemm2ph<256, 256, 2, 4, 0><<<dim3(Fdim / 256, BSz / 256), 512, 0, stream>>>(
      xb, wib, BSz, Fdim, Ddim, meta, B2, g, nullptr);

  // GEMM2: out = g * Wo^T (fp32 store)
  // 128x128 tile, 4 waves, grid 8x32 = 256 blocks, K=4096 deep pipeline
  gemm2ph<128, 128, 2, 2, 1><<<dim3(Ddim / 128, BSz / 128), 256, 0, stream>>>(
      g, wob, BSz, Ddim, Fdim, nullptr, nullptr, nullptr, out);
}